// Round 5
// baseline (485.124 us; speedup 1.0000x reference)
//
#include <hip/hip_runtime.h>
#include <hip/hip_bf16.h>
#include <math.h>
#include <stdint.h>

// ---------------------------------------------------------------------------
// HMQ MLP: fake-quant(int8) GEMM1 + bias + exact GELU -> fake-quant -> GEMM2
// int8 MFMA (mfma_i32_16x16x64_i8), exact int32 accumulation.
// R11: 8-phase barrier-paired K-loop (m201 template port). R8/R9/R10 all
// proved the 2-phase-per-K-step structure caps at ~22% MfmaUtil regardless
// of intra-step scheduling (matches m233). Now: 256x256, 8 waves, 4 phases
// per K-tile, each phase {ds_read subtile + stage issue} -> barrier ->
// lgkmcnt(0) -> setprio(1) 8xMFMA setprio(0) -> barrier. Staging split into
// half-tiles: B(kt+1)->other buf at P0 (before the ONE counted vmcnt(4) per
// K-tile), A(kt+2)->same buf at P1 (A-half consumed at P0 close). vmcnt
// never drained mid-loop.
//   - K-tile 64: A(16KB)+B(16KB) via global_load_lds (1KB/instr, linear
//     dest == int8 MFMA fragment layout: swizzle/conflict-free)
//   - launch_bounds(512,2): ~200 regs, no spill, 2 waves/SIMD
// Epilogue (unchanged from R9) aliases LDS as 8x8KB transpose regions.
// ---------------------------------------------------------------------------

typedef int    v4i    __attribute__((ext_vector_type(4)));
typedef short  short8 __attribute__((ext_vector_type(8)));
typedef int8_t char8  __attribute__((ext_vector_type(8)));

#define QMAXF 127.0f

// branch-free GELU: erf via Abramowitz-Stegun 7.1.26, |eps|<2e-7
__device__ __forceinline__ float gelu_exact(float v) {
    float z = fabsf(v) * 0.70710678118654752440f;
    float t = __builtin_amdgcn_rcpf(fmaf(0.3275911f, z, 1.0f));
    float p = fmaf(fmaf(fmaf(fmaf(1.061405429f, t, -1.453152027f), t,
                             1.421413741f), t, -0.284496736f), t,
                   0.254829592f) * t;
    float e = __expf(-z * z);
    float erfz = fmaf(-p, e, 1.0f);
    float erfv = v < 0.f ? -erfz : erfz;
    return 0.5f * v * (1.0f + erfv);
}

// ---------------- init: zero the scale slots ----------------
__global__ void init_slots(unsigned int* slots) {
    if (threadIdx.x < 8) slots[threadIdx.x] = 0u;
}

// ---------------- absmax reduction (fp32, float4) ----------------
__global__ void absmax_kernel(const float4* __restrict__ t, int n4,
                              unsigned int* __restrict__ slot) {
    float m = 0.f;
    int stride = gridDim.x * blockDim.x;
    for (int i = blockIdx.x * blockDim.x + threadIdx.x; i < n4; i += stride) {
        float4 v = t[i];
        m = fmaxf(m, fmaxf(fmaxf(fabsf(v.x), fabsf(v.y)),
                           fmaxf(fabsf(v.z), fabsf(v.w))));
    }
#pragma unroll
    for (int off = 32; off > 0; off >>= 1)
        m = fmaxf(m, __shfl_xor(m, off));
    if ((threadIdx.x & 63) == 0)
        atomicMax(slot, __float_as_uint(m));  // vals >= 0: uint order == float order
}

// ---------------- quantize fp32 -> staged int8, coalesced ----------------
__global__ void quant_stage_kernel(const float* __restrict__ x, int kshift,
                                   int nblocks, const float* __restrict__ slot,
                                   int8_t* __restrict__ q) {
    __shared__ float qt[4][1088];  // per wave: 16 rows x 68 (pad 4) floats
    const float s = fmaxf(*slot, 1e-8f) / QMAXF;
    const int lane = threadIdx.x & 63;
    const int wv   = threadIdx.x >> 6;
    const int wave0 = (blockIdx.x * blockDim.x + threadIdx.x) >> 6;
    const int nwaves = (gridDim.x * blockDim.x) >> 6;
    const int nkb = 1 << kshift;  // K/64
    const int K = 64 << kshift;
    float* tw = &qt[wv][0];
    for (int wb = wave0; wb < nblocks; wb += nwaves) {
        const int rb = wb >> kshift;
        const int kc = wb & (nkb - 1);
#pragma unroll
        for (int j = 0; j < 4; j++) {
            const int row = rb * 16 + j * 4 + (lane >> 4);
            float4 v = *(const float4*)(x + (size_t)row * K + kc * 64 + (lane & 15) * 4);
            *(float4*)(tw + (j * 4 + (lane >> 4)) * 68 + (lane & 15) * 4) = v;
        }
        int8_t tmp[16];
#pragma unroll
        for (int t = 0; t < 4; t++) {
            float4 v = *(const float4*)(tw + (lane & 15) * 68 + (lane >> 4) * 16 + t * 4);
            tmp[t*4+0] = (int8_t)fminf(fmaxf(rintf(v.x / s), -127.f), 127.f);
            tmp[t*4+1] = (int8_t)fminf(fmaxf(rintf(v.y / s), -127.f), 127.f);
            tmp[t*4+2] = (int8_t)fminf(fmaxf(rintf(v.z / s), -127.f), 127.f);
            tmp[t*4+3] = (int8_t)fminf(fmaxf(rintf(v.w / s), -127.f), 127.f);
        }
        *(int4*)(q + (size_t)wb * 1024 + lane * 16) = *(const int4*)tmp;
    }
}

// ---------------- streaming: staged int16 h -> staged int8 hq ----------
__global__ void quant_h_kernel(const short8* __restrict__ h16s,
                               const float* __restrict__ tilescale,
                               const float* __restrict__ hslot,
                               char8* __restrict__ q, int n8) {
    const float sh = fmaxf(*hslot, 1e-8f) / QMAXF;
    const float inv = 1.0f / (32767.f * sh);   // hoisted: one exact fdiv/thread
    int stride = gridDim.x * blockDim.x;
    for (int i = blockIdx.x * blockDim.x + threadIdx.x; i < n8; i += stride) {
        const int blk = i >> 7;            // (i*8)/1024
        const int rb = blk >> 6, kc = blk & 63;
        const int tile = (rb >> 3) * 32 + (kc >> 1);
        const float f = tilescale[tile] * inv;
        short8 v = h16s[i];
        char8 o;
#pragma unroll
        for (int j = 0; j < 8; j++)
            o[j] = (int8_t)fminf(fmaxf(rintf((float)v[j] * f), -127.f), 127.f);
        q[i] = o;
    }
}

// ---------------- int8 GEMM, 8-phase LDS double-buffer K-loop -------------
#define EPI_G1_STORE_I16 0   // g=gelu(..); tilemax; store staged int16
#define EPI_G1_MAXONLY   1   // g=gelu(..); atomicMax only (fallback)
#define EPI_G1_QUANT     2   // g=gelu(..); store staged int8 (fallback)
#define EPI_G2_OUT       3   // out = acc*s + b; store fp32 row-major

template <int N0>
__device__ __forceinline__ void mfma_pair(v4i (&acc)[4][8], v4i (&af)[4],
                                          v4i b0, v4i b1) {
#pragma unroll
    for (int mi = 0; mi < 4; mi++) {
        acc[mi][N0]     = __builtin_amdgcn_mfma_i32_16x16x64_i8(
            af[mi], b0, acc[mi][N0], 0, 0, 0);
        acc[mi][N0 + 1] = __builtin_amdgcn_mfma_i32_16x16x64_i8(
            af[mi], b1, acc[mi][N0 + 1], 0, 0, 0);
    }
}

template <int EPI>
__global__ __launch_bounds__(512, 2) void gemm_i8_kernel(
    const int8_t* __restrict__ A, const int8_t* __restrict__ B,
    int N, int K,
    const float* __restrict__ slotA, const float* __restrict__ slotB,
    const float* __restrict__ bias,
    int16_t* __restrict__ h16_out,        // EPI 0 (staged layout)
    float* __restrict__ tilescale,        // EPI 0
    unsigned int* __restrict__ maxslot,   // EPI 0/1
    const float* __restrict__ hslot,      // EPI 2
    int8_t* __restrict__ q_out,           // EPI 2
    float* __restrict__ out)              // EPI 3
{
    // K-loop: two 32KB operand buffers (A 16KB + B 16KB each).
    // Epilogue: aliased as 8 x 8KB wave-private int16 transpose regions.
    __shared__ __align__(16) int8_t lds[65536];
    __shared__ float red[8];

    const int tid  = threadIdx.x;
    const int lane = tid & 63;
    const int wv   = tid >> 6;     // 0..7
    const int wm   = wv & 3;       // 64-row quarter
    const int wn   = wv >> 2;      // 128-col half

    const int bm = blockIdx.x * 256;   // M fast
    const int bn = blockIdx.y * 256;
    const int nkb = K >> 6;

    const float sAB = (fmaxf(*slotA, 1e-8f) / QMAXF) *
                      (fmaxf(*slotB, 1e-8f) / QMAXF);

    v4i acc[4][8] = {};

    const size_t rbstride = (size_t)nkb * 1024;

    // half-tile staging: wave wv owns A row-chunks {2wv,2wv+1} and
    // B row-chunks {2wv,2wv+1} (16 x 1KB per half, 8 waves x 2).
    const int8_t* srcA[2];
    const int8_t* srcB[2];
#pragma unroll
    for (int j = 0; j < 2; j++) {
        srcA[j] = A + (size_t)((bm >> 4) + wv * 2 + j) * rbstride + lane * 16;
        srcB[j] = B + (size_t)((bn >> 4) + wv * 2 + j) * rbstride + lane * 16;
    }

    auto STAGE_A = [&](int buf_, int kt_) {
#pragma unroll
        for (int j = 0; j < 2; j++)
            __builtin_amdgcn_global_load_lds(
                (const __attribute__((address_space(1))) unsigned int*)
                    (srcA[j] + (size_t)kt_ * 1024),
                (__attribute__((address_space(3))) unsigned int*)
                    (lds + buf_ * 32768 + (wv * 2 + j) * 1024),
                16, 0, 0);
    };
    auto STAGE_B = [&](int buf_, int kt_) {
#pragma unroll
        for (int j = 0; j < 2; j++)
            __builtin_amdgcn_global_load_lds(
                (const __attribute__((address_space(1))) unsigned int*)
                    (srcB[j] + (size_t)kt_ * 1024),
                (__attribute__((address_space(3))) unsigned int*)
                    (lds + buf_ * 32768 + 16384 + (wv * 2 + j) * 1024),
                16, 0, 0);
    };

    // prologue: A(0),B(0) -> buf0; A(1) -> buf1  (B(1) issued at kt=0 P0)
    STAGE_A(0, 0);
    STAGE_B(0, 0);
    STAGE_A(1, 1);

    for (int kt = 0; kt < nkb; ++kt) {
        const int buf = kt & 1;
        const int8_t* pa = lds + buf * 32768 + (wm * 4) * 1024 + lane * 16;
        const int8_t* pb = lds + buf * 32768 + 16384 + (wn * 8) * 1024 + lane * 16;
        v4i af[4], bf[8];

        // ---- P0 (K-tile boundary: stage B(kt+1), ONE counted vmcnt) ----
        if (kt + 1 < nkb) {
            STAGE_B(buf ^ 1, kt + 1);        // other buf; its B-half was
            __builtin_amdgcn_sched_barrier(0);  // consumed at kt-1 P3 close
            // outstanding: [A(kt),B(kt) oldest | A(kt+1),B(kt+1) newest(4)]
            asm volatile("s_waitcnt vmcnt(4)" ::: "memory");
        } else {
            asm volatile("s_waitcnt vmcnt(0)" ::: "memory");
        }
        __builtin_amdgcn_sched_barrier(0);
        __builtin_amdgcn_s_barrier();        // kt fully staged CU-wide
        __builtin_amdgcn_sched_barrier(0);
        af[0] = *(const v4i*)(pa + 0 * 1024);
        af[1] = *(const v4i*)(pa + 1 * 1024);
        af[2] = *(const v4i*)(pa + 2 * 1024);
        af[3] = *(const v4i*)(pa + 3 * 1024);
        bf[0] = *(const v4i*)(pb + 0 * 1024);
        bf[1] = *(const v4i*)(pb + 1 * 1024);
        __builtin_amdgcn_sched_barrier(0);
        asm volatile("s_waitcnt lgkmcnt(0)" ::: "memory");
        __builtin_amdgcn_sched_barrier(0);
        __builtin_amdgcn_s_setprio(1);
        mfma_pair<0>(acc, af, bf[0], bf[1]);
        __builtin_amdgcn_s_setprio(0);
        __builtin_amdgcn_sched_barrier(0);
        __builtin_amdgcn_s_barrier();        // P0 close: A-half reads done

        // ---- P1 (stage A(kt+2) into same buf's A-half) ----
        bf[2] = *(const v4i*)(pb + 2 * 1024);
        bf[3] = *(const v4i*)(pb + 3 * 1024);
        __builtin_amdgcn_sched_barrier(0);
        if (kt + 2 < nkb) STAGE_A(buf, kt + 2);
        __builtin_amdgcn_sched_barrier(0);
        __builtin_amdgcn_s_barrier();
        asm volatile("s_waitcnt lgkmcnt(0)" ::: "memory");
        __builtin_amdgcn_sched_barrier(0);
        __builtin_amdgcn_s_setprio(1);
        mfma_pair<2>(acc, af, bf[2], bf[3]);
        __builtin_amdgcn_s_setprio(0);
        __builtin_amdgcn_sched_barrier(0);
        __builtin_amdgcn_s_barrier();

        // ---- P2 ----
        bf[4] = *(const v4i*)(pb + 4 * 1024);
        bf[5] = *(const v4i*)(pb + 5 * 1024);
        __builtin_amdgcn_sched_barrier(0);
        __builtin_amdgcn_s_barrier();
        asm volatile("s_waitcnt lgkmcnt(0)" ::: "memory");
        __builtin_amdgcn_sched_barrier(0);
        __builtin_amdgcn_s_setprio(1);
        mfma_pair<4>(acc, af, bf[4], bf[5]);
        __builtin_amdgcn_s_setprio(0);
        __builtin_amdgcn_sched_barrier(0);
        __builtin_amdgcn_s_barrier();

        // ---- P3 ----
        bf[6] = *(const v4i*)(pb + 6 * 1024);
        bf[7] = *(const v4i*)(pb + 7 * 1024);
        __builtin_amdgcn_sched_barrier(0);
        __builtin_amdgcn_s_barrier();
        asm volatile("s_waitcnt lgkmcnt(0)" ::: "memory");
        __builtin_amdgcn_sched_barrier(0);
        __builtin_amdgcn_s_setprio(1);
        mfma_pair<6>(acc, af, bf[6], bf[7]);
        __builtin_amdgcn_s_setprio(0);
        __builtin_amdgcn_sched_barrier(0);
        __builtin_amdgcn_s_barrier();        // P3 close: B-half reads done
    }

    __syncthreads();  // drain; LDS switches to epilogue transpose use

    // ---------------- epilogue ----------------
    float sc_q = 0.f;
    if constexpr (EPI == EPI_G1_QUANT) sc_q = fmaxf(*hslot, 1e-8f) / QMAXF;
    float lmax = 0.f;

    // phase 1: dequant + bias (+ GELU); park result bits back into acc regs
#pragma unroll
    for (int mi = 0; mi < 4; mi++) {
#pragma unroll
        for (int ni = 0; ni < 8; ni++) {
            const int col = bn + wn * 128 + ni * 16 + (lane & 15);
            const float bv = bias[col];
#pragma unroll
            for (int r = 0; r < 4; r++) {
                float val = (float)acc[mi][ni][r] * sAB + bv;
                if constexpr (EPI == EPI_G2_OUT) {
                    acc[mi][ni][r] = __float_as_int(val);
                } else {
                    float g = gelu_exact(val);
                    lmax = fmaxf(lmax, fabsf(g));
                    acc[mi][ni][r] = __float_as_int(g);
                }
            }
        }
    }

    float enc = 0.f;
    if constexpr (EPI == EPI_G1_STORE_I16 || EPI == EPI_G1_MAXONLY) {
#pragma unroll
        for (int off = 32; off > 0; off >>= 1)
            lmax = fmaxf(lmax, __shfl_xor(lmax, off));
        if (lane == 0) red[wv] = lmax;
        __syncthreads();
        float m = red[0];
#pragma unroll
        for (int i = 1; i < 8; i++) m = fmaxf(m, red[i]);
        if (tid == 0) {
            if constexpr (EPI == EPI_G1_STORE_I16) {
                // per-128x128 tile scale grid, row-major [M/128][N/128]
                const int TS = N >> 7;
                const int tr = bm >> 7, tc = bn >> 7;
                tilescale[(size_t)tr * TS + tc]           = m;
                tilescale[(size_t)tr * TS + tc + 1]       = m;
                tilescale[(size_t)(tr + 1) * TS + tc]     = m;
                tilescale[(size_t)(tr + 1) * TS + tc + 1] = m;
            }
            atomicMax(maxslot, __float_as_uint(m));
        }
        enc = 32767.f / fmaxf(m, 1e-20f);
    }

    // phase 2: stores
    if constexpr (EPI == EPI_G1_STORE_I16) {
        // wave-private 8KB LDS regions (aliasing operand buffer) -> no barriers
        const int r16 = (lane >> 4) * 4;
        const int c15 = lane & 15;
        int16_t* tl = (int16_t*)lds;
#pragma unroll
        for (int half = 0; half < 2; half++) {
#pragma unroll
            for (int mi = 0; mi < 4; mi++)
#pragma unroll
                for (int nih = 0; nih < 4; nih++) {
                    const int ni = half * 4 + nih;
#pragma unroll
                    for (int r = 0; r < 4; r++) {
                        float g = __int_as_float(acc[mi][ni][r]);
                        tl[wv * 4096 + mi * 1024 + nih * 256 + (r16 + r) * 16 + c15] =
                            (int16_t)rintf(g * enc);
                    }
                }
            const int kc = (bn >> 6) + wn * 2 + half;
#pragma unroll
            for (int mi = 0; mi < 4; mi++) {
                const int rb = (bm >> 4) + wm * 4 + mi;
                int16_t* dst = h16_out + ((size_t)rb * (N >> 6) + kc) * 1024;
                const int16_t* src2 = tl + wv * 4096 + mi * 1024;
                *(int4*)(dst + lane * 8)       = *(const int4*)(src2 + lane * 8);
                *(int4*)(dst + 512 + lane * 8) = *(const int4*)(src2 + 512 + lane * 8);
            }
        }
    } else if constexpr (EPI != EPI_G1_MAXONLY) {
#pragma unroll
        for (int mi = 0; mi < 4; mi++) {
            const int row0 = bm + wm * 64 + mi * 16 + (lane >> 4) * 4;
#pragma unroll
            for (int ni = 0; ni < 8; ni++) {
                const int col = bn + wn * 128 + ni * 16 + (lane & 15);
#pragma unroll
                for (int r = 0; r < 4; r++) {
                    const int row = row0 + r;
                    float g = __int_as_float(acc[mi][ni][r]);
                    if constexpr (EPI == EPI_G2_OUT) {
                        out[(size_t)row * N + col] = g;
                    } else {  // EPI_G1_QUANT fallback: staged int8 scatter
                        float qv = fminf(fmaxf(rintf(g / sc_q), -127.f), 127.f);
                        size_t off = ((size_t)(row >> 4) * (N >> 6) + (col >> 6)) * 1024
                                   + ((col >> 4) & 3) * 256 + (row & 15) * 16 + (col & 15);
                        q_out[off] = (int8_t)qv;
                    }
                }
            }
        }
    }
}

// ---------------------------------------------------------------------------

extern "C" void kernel_launch(void* const* d_in, const int* in_sizes, int n_in,
                              void* d_out, int out_size, void* d_ws, size_t ws_size,
                              hipStream_t stream) {
    const float* x  = (const float*)d_in[0];  // (4,4096,1024)
    const float* w1 = (const float*)d_in[1];  // (4096,1024)
    const float* b1 = (const float*)d_in[2];  // (4096,)
    const float* w2 = (const float*)d_in[3];  // (1024,4096)
    const float* b2 = (const float*)d_in[4];  // (1024,)
    float* out = (float*)d_out;               // (4,4096,1024) fp32

    const int D = 1024, H = 4096;
    const int Mrows = 4 * 4096;  // 16384

    // ---- workspace layout ----
    uintptr_t ws = (uintptr_t)d_ws;
    unsigned int* slots = (unsigned int*)ws;   // [0]=|x| [1]=|w1| [2]=|w2| [3]=|h|
    const float* slotf = (const float*)ws;
    float* tiles = (float*)(ws + 256);                 // 4096 tile scales
    int8_t* xq  = (int8_t*)(ws + 256 + 65536);         // staged 16 MB
    int8_t* w1q = xq + (size_t)Mrows * D;              // staged 4 MB
    int8_t* w2q = w1q + (size_t)H * D;                 // staged 4 MB
    int8_t* hq  = w2q + (size_t)D * H;                 // staged 64 MB
    int16_t* h16 = (int16_t*)(hq + (size_t)Mrows * H); // staged 128 MB
    const size_t need_i16 =
        256 + 65536 + (size_t)Mrows * D + 2u * (size_t)H * D +
        (size_t)Mrows * H + (size_t)Mrows * H * sizeof(int16_t);  // ~216 MB
    const bool use_store = ws_size >= need_i16;  // constant per session

    // ---- scales ----
    init_slots<<<dim3(1), dim3(64), 0, stream>>>(slots);
    absmax_kernel<<<dim3(1024), dim3(256), 0, stream>>>(
        (const float4*)x, Mrows * D / 4, slots + 0);
    absmax_kernel<<<dim3(256), dim3(256), 0, stream>>>(
        (const float4*)w1, H * D / 4, slots + 1);
    absmax_kernel<<<dim3(256), dim3(256), 0, stream>>>(
        (const float4*)w2, D * H / 4, slots + 2);

    // ---- quantize + stage inputs (coalesced) ----
    quant_stage_kernel<<<dim3(1024), dim3(256), 0, stream>>>(
        x, 4, (Mrows / 16) * (D / 64), slotf + 0, xq);
    quant_stage_kernel<<<dim3(256), dim3(256), 0, stream>>>(
        w1, 4, (H / 16) * (D / 64), slotf + 1, w1q);
    quant_stage_kernel<<<dim3(256), dim3(256), 0, stream>>>(
        w2, 6, (D / 16) * (H / 64), slotf + 2, w2q);

    // ---- GEMM1: (16384x1024)·(4096x1024)^T + b1, GELU ----
    dim3 g1(Mrows / 256, H / 256);  // (64, 16), M fast
    if (use_store) {
        gemm_i8_kernel<EPI_G1_STORE_I16><<<g1, dim3(512), 0, stream>>>(
            xq, w1q, H, D, slotf + 0, slotf + 1, b1,
            h16, tiles, slots + 3, nullptr, nullptr, nullptr);
        quant_h_kernel<<<dim3(2048), dim3(256), 0, stream>>>(
            (const short8*)h16, tiles, slotf + 3, (char8*)hq, Mrows * H / 8);
    } else {
        gemm_i8_kernel<EPI_G1_MAXONLY><<<g1, dim3(512), 0, stream>>>(
            xq, w1q, H, D, slotf + 0, slotf + 1, b1,
            nullptr, nullptr, slots + 3, nullptr, nullptr, nullptr);
        gemm_i8_kernel<EPI_G1_QUANT><<<g1, dim3(512), 0, stream>>>(
            xq, w1q, H, D, slotf + 0, slotf + 1, b1,
            nullptr, nullptr, nullptr, slotf + 3, hq, nullptr);
    }

    // ---- GEMM2: (16384x4096)·(1024x4096)^T + b2 -> out ----
    dim3 g2(Mrows / 256, D / 256);  // (64, 4), M fast
    gemm_i8_kernel<EPI_G2_OUT><<<g2, dim3(512), 0, stream>>>(
        hq, w2q, D, H, slotf + 3, slotf + 2, b2,
        nullptr, nullptr, nullptr, nullptr, nullptr, out);
}

// Round 6
// 438.171 us; speedup vs baseline: 1.1072x; 1.1072x over previous
//
#include <hip/hip_runtime.h>
#include <hip/hip_bf16.h>
#include <math.h>
#include <stdint.h>

// ---------------------------------------------------------------------------
// HMQ MLP: fake-quant(int8) GEMM1 + bias + exact GELU -> fake-quant -> GEMM2
// int8 MFMA (mfma_i32_16x16x64_i8), exact int32 accumulation.
// R12: REVERT GEMM to R6's barrier-free register ping-pong (best measured:
// 111us/GEMM, MfmaUtil 27%). R8-R11 proved every LDS-staged barrier
// structure (2-phase, counted-lgkm, 2-block, 8-phase) lands at 18-22%
// MfmaUtil: the barrier/wait chrome costs more than the saved L2 traffic
// at this MFMA-per-phase ratio. Remaining unexplained time (~150us) is
// inter-dispatch overhead: merge 3 absmax launches -> 1 and 3 quant_stage
// launches -> 1 (10 -> 6 dispatches/iteration). Numerics unchanged.
// ---------------------------------------------------------------------------

typedef int    v4i    __attribute__((ext_vector_type(4)));
typedef short  short8 __attribute__((ext_vector_type(8)));
typedef int8_t char8  __attribute__((ext_vector_type(8)));

#define QMAXF 127.0f

// branch-free GELU: erf via Abramowitz-Stegun 7.1.26, |eps|<2e-7
__device__ __forceinline__ float gelu_exact(float v) {
    float z = fabsf(v) * 0.70710678118654752440f;
    float t = __builtin_amdgcn_rcpf(fmaf(0.3275911f, z, 1.0f));
    float p = fmaf(fmaf(fmaf(fmaf(1.061405429f, t, -1.453152027f), t,
                             1.421413741f), t, -0.284496736f), t,
                   0.254829592f) * t;
    float e = __expf(-z * z);
    float erfz = fmaf(-p, e, 1.0f);
    float erfv = v < 0.f ? -erfz : erfz;
    return 0.5f * v * (1.0f + erfv);
}

// ---------------- init: zero the scale slots ----------------
__global__ void init_slots(unsigned int* slots) {
    if (threadIdx.x < 8) slots[threadIdx.x] = 0u;
}

// ---------------- merged absmax: x | w1 | w2 in one dispatch ----------------
// blocks [0,1024) -> x ; [1024,1280) -> w1 ; [1280,1536) -> w2
__global__ void absmax3_kernel(const float4* __restrict__ x,
                               const float4* __restrict__ w1,
                               const float4* __restrict__ w2,
                               unsigned int* __restrict__ slots) {
    const float4* t;
    int n4, b0, nb;
    unsigned int* slot;
    const int b = blockIdx.x;
    if (b < 1024)      { t = x;  n4 = (4 * 4096 * 1024) / 4; slot = slots + 0; b0 = 0;    nb = 1024; }
    else if (b < 1280) { t = w1; n4 = (4096 * 1024) / 4;     slot = slots + 1; b0 = 1024; nb = 256; }
    else               { t = w2; n4 = (4096 * 1024) / 4;     slot = slots + 2; b0 = 1280; nb = 256; }

    float m = 0.f;
    const int stride = nb * blockDim.x;
    for (int i = (b - b0) * blockDim.x + threadIdx.x; i < n4; i += stride) {
        float4 v = t[i];
        m = fmaxf(m, fmaxf(fmaxf(fabsf(v.x), fabsf(v.y)),
                           fmaxf(fabsf(v.z), fabsf(v.w))));
    }
#pragma unroll
    for (int off = 32; off > 0; off >>= 1)
        m = fmaxf(m, __shfl_xor(m, off));
    if ((threadIdx.x & 63) == 0)
        atomicMax(slot, __float_as_uint(m));  // vals >= 0: uint order == float order
}

// ---------------- merged quantize+stage: x | w1 | w2 in one dispatch -------
// One wave per 1KB-dest block (16 rows x 64 k). Reads 4x 1KB instrs covering
// 4 full 256B row-segments each (coalesced); transposes via wave-private LDS;
// writes 1KB contiguous. Global waves [0,4096)->x, [4096,5120)->w1,
// [5120,6144)->w2 (grid must be 1536 x 256).
__global__ void quant_stage3_kernel(const float* __restrict__ x,
                                    const float* __restrict__ w1,
                                    const float* __restrict__ w2,
                                    const float* __restrict__ slotf,
                                    int8_t* __restrict__ xq,
                                    int8_t* __restrict__ w1q,
                                    int8_t* __restrict__ w2q) {
    __shared__ float qt[4][1088];  // per wave: 16 rows x 68 (pad 4) floats
    const int lane = threadIdx.x & 63;
    const int wvl  = threadIdx.x >> 6;
    const int gw   = (blockIdx.x * blockDim.x + threadIdx.x) >> 6;

    const float* src;
    int8_t* q;
    const float* slot;
    int wave0, nwaves, nblocks, kshift;
    if (gw < 4096)      { src = x;  q = xq;  slot = slotf + 0; wave0 = gw;        nwaves = 4096; nblocks = 16384; kshift = 4; }
    else if (gw < 5120) { src = w1; q = w1q; slot = slotf + 1; wave0 = gw - 4096; nwaves = 1024; nblocks = 4096;  kshift = 4; }
    else                { src = w2; q = w2q; slot = slotf + 2; wave0 = gw - 5120; nwaves = 1024; nblocks = 4096;  kshift = 6; }

    const float s = fmaxf(*slot, 1e-8f) / QMAXF;
    const int nkb = 1 << kshift;  // K/64
    const int K = 64 << kshift;
    float* tw = &qt[wvl][0];
    for (int wb = wave0; wb < nblocks; wb += nwaves) {
        const int rb = wb >> kshift;
        const int kc = wb & (nkb - 1);
        // coalesced read: instr j covers rows rb*16+j*4..+3, 256B per row
#pragma unroll
        for (int j = 0; j < 4; j++) {
            const int row = rb * 16 + j * 4 + (lane >> 4);
            float4 v = *(const float4*)(src + (size_t)row * K + kc * 64 + (lane & 15) * 4);
            *(float4*)(tw + (j * 4 + (lane >> 4)) * 68 + (lane & 15) * 4) = v;
        }
        // fragment gather: lane -> row15 = lane&15, k-chunk = (lane>>4)*16
        int8_t tmp[16];
#pragma unroll
        for (int t = 0; t < 4; t++) {
            float4 v = *(const float4*)(tw + (lane & 15) * 68 + (lane >> 4) * 16 + t * 4);
            tmp[t*4+0] = (int8_t)fminf(fmaxf(rintf(v.x / s), -127.f), 127.f);
            tmp[t*4+1] = (int8_t)fminf(fmaxf(rintf(v.y / s), -127.f), 127.f);
            tmp[t*4+2] = (int8_t)fminf(fmaxf(rintf(v.z / s), -127.f), 127.f);
            tmp[t*4+3] = (int8_t)fminf(fmaxf(rintf(v.w / s), -127.f), 127.f);
        }
        *(int4*)(q + (size_t)wb * 1024 + lane * 16) = *(const int4*)tmp;
    }
}

// ---------------- streaming: staged int16 h -> staged int8 hq ----------
__global__ void quant_h_kernel(const short8* __restrict__ h16s,
                               const float* __restrict__ tilescale,
                               const float* __restrict__ hslot,
                               char8* __restrict__ q, int n8) {
    const float sh = fmaxf(*hslot, 1e-8f) / QMAXF;
    const float inv = 1.0f / (32767.f * sh);   // hoisted: one exact fdiv/thread
    int stride = gridDim.x * blockDim.x;
    for (int i = blockIdx.x * blockDim.x + threadIdx.x; i < n8; i += stride) {
        const int blk = i >> 7;            // (i*8)/1024
        const int rb = blk >> 6, kc = blk & 63;
        const int tile = (rb >> 3) * 32 + (kc >> 1);
        const float f = tilescale[tile] * inv;
        short8 v = h16s[i];
        char8 o;
#pragma unroll
        for (int j = 0; j < 8; j++)
            o[j] = (int8_t)fminf(fmaxf(rintf((float)v[j] * f), -127.f), 127.f);
        q[i] = o;
    }
}

// ---------------- int8 GEMM on staged operands, no LDS in K-loop ----------
// (R6 structure: register ping-pong, no barriers in the K-loop.)
#define EPI_G1_STORE_I16 0   // g=gelu(..); tilemax; store staged int16
#define EPI_G1_MAXONLY   1   // g=gelu(..); atomicMax only (fallback)
#define EPI_G1_QUANT     2   // g=gelu(..); store staged int8 (fallback)
#define EPI_G2_OUT       3   // out = acc*s + b; store fp32 row-major

template <int EPI>
__global__ __launch_bounds__(256, 2) void gemm_i8_kernel(
    const int8_t* __restrict__ A, const int8_t* __restrict__ B,
    int N, int K,
    const float* __restrict__ slotA, const float* __restrict__ slotB,
    const float* __restrict__ bias,
    int16_t* __restrict__ h16_out,        // EPI 0 (staged layout)
    float* __restrict__ tilescale,        // EPI 0
    unsigned int* __restrict__ maxslot,   // EPI 0/1
    const float* __restrict__ hslot,      // EPI 2
    int8_t* __restrict__ q_out,           // EPI 2
    float* __restrict__ out)              // EPI 3
{
    __shared__ __align__(16) int16_t tl[16384];  // epilogue transpose (32 KB)
    __shared__ float red[4];

    const int tid  = threadIdx.x;
    const int lane = tid & 63;
    const int wv   = tid >> 6;
    const int wm   = wv & 1;    // 64-row half
    const int wn   = wv >> 1;   // 128-col half

    const int bm = blockIdx.x * 128;   // M fast
    const int bn = blockIdx.y * 256;
    const int nkb = K >> 6;

    const float sAB = (fmaxf(*slotA, 1e-8f) / QMAXF) *
                      (fmaxf(*slotB, 1e-8f) / QMAXF);

    v4i acc[4][8] = {};

    const size_t rbstride = (size_t)nkb * 1024;
    const int8_t* pA = A + (size_t)((bm >> 4) + wm * 4) * rbstride + lane * 16;
    const int8_t* pB = B + (size_t)((bn >> 4) + wn * 8) * rbstride + lane * 16;

    auto loadA = [&](v4i (&d)[4], int k) {
#pragma unroll
        for (int i = 0; i < 4; i++)
            d[i] = *(const v4i*)(pA + (size_t)i * rbstride + (size_t)k * 1024);
    };
    auto loadB = [&](v4i (&d)[8], int k) {
#pragma unroll
        for (int i = 0; i < 8; i++)
            d[i] = *(const v4i*)(pB + (size_t)i * rbstride + (size_t)k * 1024);
    };
    auto mfma_all = [&](v4i (&a)[4], v4i (&b)[8]) {
#pragma unroll
        for (int mi = 0; mi < 4; mi++)
#pragma unroll
            for (int ni = 0; ni < 8; ni++)
                acc[mi][ni] = __builtin_amdgcn_mfma_i32_16x16x64_i8(
                    a[mi], b[ni], acc[mi][ni], 0, 0, 0);
    };

    // register ping-pong pipeline, no barriers
    v4i a0[4], a1[4];
    v4i b0[8], b1[8];
    loadA(a0, 0); loadB(b0, 0);
    loadA(a1, 1); loadB(b1, 1);
    int kt = 0;
    for (; kt + 2 < nkb; kt += 2) {
        mfma_all(a0, b0);
        loadA(a0, kt + 2); loadB(b0, kt + 2);
        mfma_all(a1, b1);
        loadA(a1, kt + 3); loadB(b1, kt + 3);
    }
    mfma_all(a0, b0);
    mfma_all(a1, b1);

    // ---------------- epilogue ----------------
    float sc_q = 0.f;
    if constexpr (EPI == EPI_G1_QUANT) sc_q = fmaxf(*hslot, 1e-8f) / QMAXF;
    float lmax = 0.f;

    // phase 1: dequant + bias (+ GELU); park result bits back into acc regs
#pragma unroll
    for (int mi = 0; mi < 4; mi++) {
#pragma unroll
        for (int ni = 0; ni < 8; ni++) {
            const int col = bn + wn * 128 + ni * 16 + (lane & 15);
            const float bv = bias[col];
#pragma unroll
            for (int r = 0; r < 4; r++) {
                float val = (float)acc[mi][ni][r] * sAB + bv;
                if constexpr (EPI == EPI_G2_OUT) {
                    acc[mi][ni][r] = __float_as_int(val);
                } else {
                    float g = gelu_exact(val);
                    lmax = fmaxf(lmax, fabsf(g));
                    acc[mi][ni][r] = __float_as_int(g);
                }
            }
        }
    }

    float enc = 0.f;
    if constexpr (EPI == EPI_G1_STORE_I16 || EPI == EPI_G1_MAXONLY) {
#pragma unroll
        for (int off = 32; off > 0; off >>= 1)
            lmax = fmaxf(lmax, __shfl_xor(lmax, off));
        if (lane == 0) red[wv] = lmax;
        __syncthreads();
        const float m = fmaxf(fmaxf(red[0], red[1]), fmaxf(red[2], red[3]));
        if (tid == 0) {
            if constexpr (EPI == EPI_G1_STORE_I16) {
                const int tbase = blockIdx.x * (gridDim.y * 2) + blockIdx.y * 2;
                tilescale[tbase]     = m;
                tilescale[tbase + 1] = m;
            }
            atomicMax(maxslot, __float_as_uint(m));
        }
        enc = 32767.f / fmaxf(m, 1e-20f);
    }

    // phase 2: stores
    if constexpr (EPI == EPI_G1_STORE_I16) {
        // two 32KB halves; wave-private LDS regions -> no barriers needed
        const int r16 = (lane >> 4) * 4;
        const int c15 = lane & 15;
#pragma unroll
        for (int half = 0; half < 2; half++) {
#pragma unroll
            for (int mi = 0; mi < 4; mi++)
#pragma unroll
                for (int nih = 0; nih < 4; nih++) {
                    const int ni = half * 4 + nih;
#pragma unroll
                    for (int r = 0; r < 4; r++) {
                        float g = __int_as_float(acc[mi][ni][r]);
                        tl[wv * 4096 + mi * 1024 + nih * 256 + (r16 + r) * 16 + c15] =
                            (int16_t)rintf(g * enc);
                    }
                }
            const int kc = (bn >> 6) + wn * 2 + half;
#pragma unroll
            for (int mi = 0; mi < 4; mi++) {
                const int rb = (bm >> 4) + wm * 4 + mi;
                int16_t* dst = h16_out + ((size_t)rb * (N >> 6) + kc) * 1024;
                const int16_t* src = tl + wv * 4096 + mi * 1024;
                *(int4*)(dst + lane * 8)       = *(const int4*)(src + lane * 8);
                *(int4*)(dst + 512 + lane * 8) = *(const int4*)(src + 512 + lane * 8);
            }
        }
    } else if constexpr (EPI != EPI_G1_MAXONLY) {
#pragma unroll
        for (int mi = 0; mi < 4; mi++) {
            const int row0 = bm + wm * 64 + mi * 16 + (lane >> 4) * 4;
#pragma unroll
            for (int ni = 0; ni < 8; ni++) {
                const int col = bn + wn * 128 + ni * 16 + (lane & 15);
#pragma unroll
                for (int r = 0; r < 4; r++) {
                    const int row = row0 + r;
                    float g = __int_as_float(acc[mi][ni][r]);
                    if constexpr (EPI == EPI_G2_OUT) {
                        out[(size_t)row * N + col] = g;
                    } else {  // EPI_G1_QUANT fallback: staged int8 scatter
                        float qv = fminf(fmaxf(rintf(g / sc_q), -127.f), 127.f);
                        size_t off = ((size_t)(row >> 4) * (N >> 6) + (col >> 6)) * 1024
                                   + ((col >> 4) & 3) * 256 + (row & 15) * 16 + (col & 15);
                        q_out[off] = (int8_t)qv;
                    }
                }
            }
        }
    }
}

// ---------------------------------------------------------------------------

extern "C" void kernel_launch(void* const* d_in, const int* in_sizes, int n_in,
                              void* d_out, int out_size, void* d_ws, size_t ws_size,
                              hipStream_t stream) {
    const float* x  = (const float*)d_in[0];  // (4,4096,1024)
    const float* w1 = (const float*)d_in[1];  // (4096,1024)
    const float* b1 = (const float*)d_in[2];  // (4096,)
    const float* w2 = (const float*)d_in[3];  // (1024,4096)
    const float* b2 = (const float*)d_in[4];  // (1024,)
    float* out = (float*)d_out;               // (4,4096,1024) fp32

    const int D = 1024, H = 4096;
    const int Mrows = 4 * 4096;  // 16384

    // ---- workspace layout ----
    uintptr_t ws = (uintptr_t)d_ws;
    unsigned int* slots = (unsigned int*)ws;   // [0]=|x| [1]=|w1| [2]=|w2| [3]=|h|
    const float* slotf = (const float*)ws;
    float* tiles = (float*)(ws + 256);                 // 4096 tile scales
    int8_t* xq  = (int8_t*)(ws + 256 + 65536);         // staged 16 MB
    int8_t* w1q = xq + (size_t)Mrows * D;              // staged 4 MB
    int8_t* w2q = w1q + (size_t)H * D;                 // staged 4 MB
    int8_t* hq  = w2q + (size_t)D * H;                 // staged 64 MB
    int16_t* h16 = (int16_t*)(hq + (size_t)Mrows * H); // staged 128 MB
    const size_t need_i16 =
        256 + 65536 + (size_t)Mrows * D + 2u * (size_t)H * D +
        (size_t)Mrows * H + (size_t)Mrows * H * sizeof(int16_t);  // ~216 MB
    const bool use_store = ws_size >= need_i16;  // constant per session

    // ---- scales (merged: 1 launch) ----
    init_slots<<<dim3(1), dim3(64), 0, stream>>>(slots);
    absmax3_kernel<<<dim3(1536), dim3(256), 0, stream>>>(
        (const float4*)x, (const float4*)w1, (const float4*)w2, slots);

    // ---- quantize + stage inputs (merged: 1 launch) ----
    quant_stage3_kernel<<<dim3(1536), dim3(256), 0, stream>>>(
        x, w1, w2, slotf, xq, w1q, w2q);

    // ---- GEMM1: (16384x1024)·(4096x1024)^T + b1, GELU ----
    dim3 g1(Mrows / 128, H / 256);  // (128, 16), M fast
    if (use_store) {
        gemm_i8_kernel<EPI_G1_STORE_I16><<<g1, dim3(256), 0, stream>>>(
            xq, w1q, H, D, slotf + 0, slotf + 1, b1,
            h16, tiles, slots + 3, nullptr, nullptr, nullptr);
        quant_h_kernel<<<dim3(2048), dim3(256), 0, stream>>>(
            (const short8*)h16, tiles, slotf + 3, (char8*)hq, Mrows * H / 8);
    } else {
        gemm_i8_kernel<EPI_G1_MAXONLY><<<g1, dim3(256), 0, stream>>>(
            xq, w1q, H, D, slotf + 0, slotf + 1, b1,
            nullptr, nullptr, slots + 3, nullptr, nullptr, nullptr);
        gemm_i8_kernel<EPI_G1_QUANT><<<g1, dim3(256), 0, stream>>>(
            xq, w1q, H, D, slotf + 0, slotf + 1, b1,
            nullptr, nullptr, nullptr, slotf + 3, hq, nullptr);
    }

    // ---- GEMM2: (16384x4096)·(1024x4096)^T + b2 -> out ----
    dim3 g2(Mrows / 128, D / 256);  // (128, 4), M fast
    gemm_i8_kernel<EPI_G2_OUT><<<g2, dim3(256), 0, stream>>>(
        hq, w2q, D, H, slotf + 3, slotf + 2, b2,
        nullptr, nullptr, nullptr, nullptr, nullptr, out);
}